// Round 12
// baseline (28.026 us; speedup 1.0000x reference)
//
#include <hip/hip_runtime.h>
#include <math.h>

#define NF 32
#define NE 64
#define NA 64
#define NP 496
#define W1T_S 72   // padded stride (f16) of W1t: 144B, 16B-aligned

typedef __attribute__((ext_vector_type(8))) _Float16 f16x8;
typedef __attribute__((ext_vector_type(4))) _Float16 f16x4;
typedef __attribute__((ext_vector_type(4))) float    f32x4;

// Block = 256 thr = 2 samples x 2 waves. Fused logit->exp->oacc (R10), but each
// sample split across 2 waves (toff range) to restore TLP (R10 was 2 waves/SIMD
// structural; the fused chain had nothing to hide behind). Partials combine in
// LDS behind bar2. launch_bounds(256,1): R9's tighter cap spilled to scratch.
__global__ __launch_bounds__(256, 1) void afm_fwd(
    const float* __restrict__ x,    // (B,32,64)
    const float* __restrict__ W1,   // (64,64)
    const float* __restrict__ b1,   // (64)
    const float* __restrict__ w2,   // (64,1)
    const float* __restrict__ b2,   // (1)
    float* __restrict__ out,        // (B,64)
    float* __restrict__ attn,       // (B,496)
    int B)
{
    const int tid   = threadIdx.x;
    const int lane  = tid & 63;
    const int wv    = tid >> 6;
    const int smp   = wv >> 1;      // sample slot (0/1)
    const int sub   = wv & 1;       // wave within sample
    const int nlane = lane & 15;
    const int g     = lane >> 4;

    __shared__ __align__(16) _Float16 W1t[64][W1T_S];   // 9216 B
    __shared__ __align__(16) _Float16 xh[2][8][NF][8];  // 8192 B
    __shared__ float s_w[2][NP];                        // 3968 B raw exp weights
    __shared__ float s_red[2][2][68];                   // 2176 B partial oacc+sw
    // total 23552 B

    // ---- block-cooperative: W1 -> W1t (f16, transposed) ----
    {
        const int e = tid & 63, a0 = (tid >> 6) << 4;
        const float* wr = W1 + e * NA + a0;
        #pragma unroll
        for (int i = 0; i < 4; ++i) {
            const float4 v = *(const float4*)(wr + 4 * i);
            W1t[a0 + 4*i + 0][e] = (_Float16)v.x;
            W1t[a0 + 4*i + 1][e] = (_Float16)v.y;
            W1t[a0 + 4*i + 2][e] = (_Float16)v.z;
            W1t[a0 + 4*i + 3][e] = (_Float16)v.w;
        }
    }

    int b = blockIdx.x * 2 + smp;
    if (b >= B) b = B - 1;          // benign dup-compute guard

    // ---- stage x[b]: this wave stages rows sub*16..+15 (16 rows x 64 e) ----
    const float* __restrict__ xb = x + (size_t)b * (NF * NE);
    {
        const int r  = sub * 16 + (lane >> 2);
        const int e0 = (lane & 3) << 4;
        #pragma unroll
        for (int i = 0; i < 4; ++i) {
            const int e = e0 + 4 * i;
            const float4 v = *(const float4*)(xb + r * NE + e);
            f16x4 hv = { (_Float16)v.x, (_Float16)v.y, (_Float16)v.z, (_Float16)v.w };
            *(f16x4*)&xh[smp][e >> 3][r][e & 7] = hv;
        }
    }
    __syncthreads();   // bar1: W1t + xh ready

    // ---- W1 A-frags from LDS (8 x ds_read_b128) ----
    f16x8 w1f[2][4];
    #pragma unroll
    for (int s = 0; s < 2; ++s)
        #pragma unroll
        for (int mt = 0; mt < 4; ++mt)
            w1f[s][mt] = *(const f16x8*)&W1t[mt * 16 + nlane][s * 32 + g * 8];

    f32x4 b1q[4], w2q[4];
    #pragma unroll
    for (int mt = 0; mt < 4; ++mt) {
        b1q[mt] = *(const f32x4*)(b1 + mt * 16 + g * 4);   // a = 16mt+4g+reg
        w2q[mt] = *(const f32x4*)(w2 + mt * 16 + g * 4);
    }
    const float bias2 = b2[0];

    // ---- per-lane (r,c) walk: pairs p = 31*nlane + toff, toff = 16*sub + t ----
    int pr, pc;
    {
        const int p0 = 31 * nlane + 16 * sub;
        const float sq = sqrtf((float)(3969 - 8 * p0));
        int r = (int)((63.0f - sq) * 0.5f);
        int st = (r * (63 - r)) >> 1;
        if (p0 < st) { --r; st = (r * (63 - r)) >> 1; }
        else { const int st2 = ((r + 1) * (62 - r)) >> 1; if (p0 >= st2) { ++r; st = st2; } }
        pr = r; pc = p0 - st + r + 1;
    }

    float oacc0[8] = {0,0,0,0,0,0,0,0};   // e = 8g + j
    float oacc1[8] = {0,0,0,0,0,0,0,0};   // e = 32 + 8g + j
    float sw = 0.0f;

    const int tcnt = 16 - sub;            // sub0: 16 tiles, sub1: 15
    for (int t = 0; t < tcnt; ++t) {
        const f16x8 xr0 = *(const f16x8*)&xh[smp][g][pr][0];
        const f16x8 xc0 = *(const f16x8*)&xh[smp][g][pc][0];
        const f16x8 xr1 = *(const f16x8*)&xh[smp][4 + g][pr][0];
        const f16x8 xc1 = *(const f16x8*)&xh[smp][4 + g][pc][0];
        const f16x8 af0 = xr0 * xc0;                     // inner[p, e-slice]
        const f16x8 af1 = xr1 * xc1;

        f32x4 acc[4];
        #pragma unroll
        for (int mt = 0; mt < 4; ++mt) acc[mt] = b1q[mt];
        __builtin_amdgcn_s_setprio(1);
        #pragma unroll
        for (int mt = 0; mt < 4; ++mt)
            acc[mt] = __builtin_amdgcn_mfma_f32_16x16x32_f16(w1f[0][mt], af0, acc[mt], 0, 0, 0);
        #pragma unroll
        for (int mt = 0; mt < 4; ++mt)
            acc[mt] = __builtin_amdgcn_mfma_f32_16x16x32_f16(w1f[1][mt], af1, acc[mt], 0, 0, 0);
        __builtin_amdgcn_s_setprio(0);

        float pl0 = 0.f, pl1 = 0.f, pl2 = 0.f, pl3 = 0.f;
        #pragma unroll
        for (int mt = 0; mt < 4; ++mt) {
            pl0 = fmaf(fmaxf(acc[mt][0], 0.f), w2q[mt][0], pl0);
            pl1 = fmaf(fmaxf(acc[mt][1], 0.f), w2q[mt][1], pl1);
            pl2 = fmaf(fmaxf(acc[mt][2], 0.f), w2q[mt][2], pl2);
            pl3 = fmaf(fmaxf(acc[mt][3], 0.f), w2q[mt][3], pl3);
        }
        float logit = (pl0 + pl1) + (pl2 + pl3);
        logit += __shfl_xor(logit, 16);
        logit += __shfl_xor(logit, 32);                  // uniform across g

        const float w = __expf(logit + bias2);           // raw exp (R4-verified)
        if (lane < 16) s_w[smp][31 * lane + 16 * sub + t] = w;
        sw += w;
        #pragma unroll
        for (int j = 0; j < 8; ++j) {
            oacc0[j] = fmaf(w, (float)af0[j], oacc0[j]); // v_fma_mix
            oacc1[j] = fmaf(w, (float)af1[j], oacc1[j]);
        }

        // advance (r,c) -> next pair (branchless)
        ++pc;
        const int wrap = (pc >= 32) ? 1 : 0;
        pr += wrap;
        pc = wrap ? (pr + 1) : pc;
    }

    // ---- cross-nlane reduce (pairs partitioned by nlane; 4 shuffle steps) ----
    #pragma unroll
    for (int off = 1; off < 16; off <<= 1) {
        sw += __shfl_xor(sw, off);
        #pragma unroll
        for (int j = 0; j < 8; ++j) {
            oacc0[j] += __shfl_xor(oacc0[j], off);
            oacc1[j] += __shfl_xor(oacc1[j], off);
        }
    }

    // ---- write this wave's partials (e-slices live on nlane==0 lanes) ----
    if (nlane == 0) {
        float* rd = &s_red[smp][sub][0];
        #pragma unroll
        for (int j = 0; j < 8; ++j) {
            rd[8 * g + j]      = oacc0[j];
            rd[32 + 8 * g + j] = oacc1[j];
        }
        if (g == 0) rd[64] = sw;
    }
    __syncthreads();   // bar2: partials + s_w complete

    const float inv = 1.0f / (s_red[smp][0][64] + s_red[smp][1][64]);

    // ---- out: wave sub writes e-half sub*32..+31 (combined partials) ----
    if (lane < 32) {
        const int e = sub * 32 + lane;
        out[(size_t)b * NE + e] = (s_red[smp][0][e] + s_red[smp][1][e]) * inv;
    }

    // ---- attn: wave sub writes p-range [256*sub, 256*sub+256) ----
    float* __restrict__ attn_b = attn + (size_t)b * NP;
    #pragma unroll
    for (int k = 0; k < 4; ++k) {
        const int p = ((4 * sub + k) << 6) + lane;
        if (p < NP) attn_b[p] = s_w[smp][p] * inv;
    }
}

extern "C" void kernel_launch(void* const* d_in, const int* in_sizes, int n_in,
                              void* d_out, int out_size, void* d_ws, size_t ws_size,
                              hipStream_t stream) {
    const float* x  = (const float*)d_in[0];
    const float* W1 = (const float*)d_in[1];
    const float* b1 = (const float*)d_in[2];
    const float* w2 = (const float*)d_in[3];
    const float* b2 = (const float*)d_in[4];

    const int B = in_sizes[0] / (NF * NE);             // 2048
    float* out_p  = (float*)d_out;                     // (B,1,64) flat
    float* attn_p = (float*)d_out + (size_t)B * NE;    // (B,496,1) flat

    afm_fwd<<<(B + 1) / 2, 256, 0, stream>>>(x, W1, b1, w2, b2, out_p, attn_p, B);
}

// Round 14
// 24.493 us; speedup vs baseline: 1.1442x; 1.1442x over previous
//
#include <hip/hip_runtime.h>
#include <math.h>

#define NF 32
#define NE 64
#define NA 64
#define NP 496

typedef __attribute__((ext_vector_type(8))) _Float16 f16x8;
typedef __attribute__((ext_vector_type(4))) _Float16 f16x4;
typedef __attribute__((ext_vector_type(2))) __fp16   h16x2;   // cvt_pkrtz/fdot2 type
typedef __attribute__((ext_vector_type(4))) float    f32x4;

#define W1T_S 72   // padded stride (f16) of W1t
#define XT_S  40   // padded stride (f16) of xT
#define WT_S  40   // padded stride (f16) of Wt

// R9 (22.4us) structure, VALU-cut: (1) b1 folded into MFMA C-operand (D!=C,
// deletes 16 init movs/tile = 1 VALU/elem); (2) packed relu-dot epilogue via
// cvt_pkrtz + pk_max + fdot2 (24 inst vs 32, f32 accumulation kept).
__global__ __launch_bounds__(256, 1) void afm_fwd(
    const float* __restrict__ x,    // (B,32,64)
    const float* __restrict__ W1,   // (64,64)
    const float* __restrict__ b1,   // (64)
    const float* __restrict__ w2,   // (64,1)
    const float* __restrict__ b2,   // (1)
    float* __restrict__ out,        // (B,64)
    float* __restrict__ attn,       // (B,496)
    int B)
{
    const int tid   = threadIdx.x;
    const int lane  = tid & 63;
    const int wv    = tid >> 6;
    const int smp   = wv >> 1;      // sample slot in block (0/1)
    const int sub   = wv & 1;       // wave within the sample pair
    const int nlane = lane & 15;
    const int g     = lane >> 4;

    __shared__ __align__(16) _Float16 W1t[64][W1T_S];      // 9216 B
    __shared__ __align__(16) _Float16 xh[2][8][NF][8];     // 8192 B
    __shared__ __align__(16) _Float16 xT[2][NE][XT_S];     // 10240 B
    __shared__ __align__(16) _Float16 Wt[2][NF][WT_S];     // 5120 B
    __shared__ float s_l[2][NP];                           // 3968 B
    __shared__ unsigned short s_rc[512];                   // 1024 B

    // ---- block-cooperative: W1 -> W1t (f16, transposed), pair table ----
    {
        const int e = tid & 63, a0 = (tid >> 6) << 4;
        const float* wr = W1 + e * NA + a0;
        #pragma unroll
        for (int i = 0; i < 4; ++i) {
            const float4 v = *(const float4*)(wr + 4 * i);
            W1t[a0 + 4*i + 0][e] = (_Float16)v.x;
            W1t[a0 + 4*i + 1][e] = (_Float16)v.y;
            W1t[a0 + 4*i + 2][e] = (_Float16)v.z;
            W1t[a0 + 4*i + 3][e] = (_Float16)v.w;
        }
    }
    for (int p = tid; p < 512; p += 256) {
        const int pp = (p < NP) ? p : NP - 1;
        const float sq = sqrtf((float)(3969 - 8 * pp));
        int r = (int)((63.0f - sq) * 0.5f);
        int st = (r * (63 - r)) >> 1;
        if (pp < st) { --r; st = (r * (63 - r)) >> 1; }
        else { const int st2 = ((r + 1) * (62 - r)) >> 1; if (pp >= st2) { ++r; st = st2; } }
        const int c = pp - st + r + 1;
        s_rc[p] = (unsigned short)(r | (c << 8));
    }

    int b = blockIdx.x * 2 + smp;
    if (b >= B) b = B - 1;          // benign dup-compute guard

    // ---- zero Wt[smp] (ordering rides bar1+bar2) ----
    {
        unsigned int* wz = (unsigned int*)&Wt[smp][0][0];  // 640 u32 per sample
        #pragma unroll
        for (int i = 0; i < 5; ++i) {
            const int idx = i * 64 + lane;
            if (idx < 320) wz[sub * 320 + idx] = 0u;
        }
    }

    // ---- stage x[b] halves -> xh (e-subtiled) and xT (transposed) ----
    const float* __restrict__ xb = x + (size_t)b * (NF * NE);
    {
        const int r  = sub * 16 + (lane >> 2);             // 16 rows per wave
        const int e0 = (lane & 3) << 4;
        #pragma unroll
        for (int i = 0; i < 4; ++i) {
            const int e = e0 + 4 * i;
            const float4 v = *(const float4*)(xb + r * NE + e);
            f16x4 hv = { (_Float16)v.x, (_Float16)v.y, (_Float16)v.z, (_Float16)v.w };
            *(f16x4*)&xh[smp][e >> 3][r][e & 7] = hv;
            xT[smp][e + 0][r] = hv[0];
            xT[smp][e + 1][r] = hv[1];
            xT[smp][e + 2][r] = hv[2];
            xT[smp][e + 3][r] = hv[3];
        }
    }

    // ---- per-lane (r,c) for striped pairs p = 31*nlane + 16*sub + t ----
    int pr, pc;
    {
        const int p0 = 31 * nlane + 16 * sub;
        const float sq = sqrtf((float)(3969 - 8 * p0));
        int r = (int)((63.0f - sq) * 0.5f);
        int st = (r * (63 - r)) >> 1;
        if (p0 < st) { --r; st = (r * (63 - r)) >> 1; }
        else { const int st2 = ((r + 1) * (62 - r)) >> 1; if (p0 >= st2) { ++r; st = st2; } }
        pr = r;
        pc = p0 - st + r + 1;
    }
    __syncthreads();   // bar1: W1t/rc/x-staging/Wt-zero done

    // ---- W1 A-frags from LDS (8 x ds_read_b128) ----
    f16x8 w1f[2][4];
    #pragma unroll
    for (int s = 0; s < 2; ++s)
        #pragma unroll
        for (int mt = 0; mt < 4; ++mt)
            w1f[s][mt] = *(const f16x8*)&W1t[mt * 16 + nlane][s * 32 + g * 8];

    f32x4 b1q[4];
    h16x2 w2h[4][2];
    #pragma unroll
    for (int mt = 0; mt < 4; ++mt) {
        b1q[mt] = *(const f32x4*)(b1 + mt * 16 + g * 4);   // a = 16mt+4g+reg
        const f32x4 wq = *(const f32x4*)(w2 + mt * 16 + g * 4);
        w2h[mt][0] = (h16x2){ (__fp16)wq[0], (__fp16)wq[1] };
        w2h[mt][1] = (h16x2){ (__fp16)wq[2], (__fp16)wq[3] };
    }
    const float bias2 = b2[0];
    const h16x2 zz = { (__fp16)0.0f, (__fp16)0.0f };

    // ---- phase 1: 16 (sub0) / 15 (sub1) tiles; rc in registers ----
    #pragma unroll
    for (int t = 0; t < 16; ++t) {
        if (16 * sub + t < 31) {
            f16x8 af[2];
            #pragma unroll
            for (int s = 0; s < 2; ++s) {
                const f16x8 xr8 = *(const f16x8*)&xh[smp][4 * s + g][pr][0];
                const f16x8 xc8 = *(const f16x8*)&xh[smp][4 * s + g][pc][0];
                af[s] = xr8 * xc8;
            }
            // b1 folded into C-operand of the first MFMA (D != C: no init movs)
            f32x4 acc[4];
            __builtin_amdgcn_s_setprio(1);
            #pragma unroll
            for (int mt = 0; mt < 4; ++mt)
                acc[mt] = __builtin_amdgcn_mfma_f32_16x16x32_f16(w1f[0][mt], af[0], b1q[mt], 0, 0, 0);
            #pragma unroll
            for (int mt = 0; mt < 4; ++mt)
                acc[mt] = __builtin_amdgcn_mfma_f32_16x16x32_f16(w1f[1][mt], af[1], acc[mt], 0, 0, 0);
            __builtin_amdgcn_s_setprio(0);

            // packed relu-dot: cvt_pkrtz -> pk_max -> fdot2 (f32 accumulate)
            float plA = 0.f, plB = 0.f;
            #pragma unroll
            for (int mt = 0; mt < 4; ++mt) {
                h16x2 h01 = __builtin_amdgcn_cvt_pkrtz(acc[mt][0], acc[mt][1]);
                h16x2 h23 = __builtin_amdgcn_cvt_pkrtz(acc[mt][2], acc[mt][3]);
                h01 = __builtin_elementwise_max(h01, zz);
                h23 = __builtin_elementwise_max(h23, zz);
                plA = __builtin_amdgcn_fdot2(h01, w2h[mt][0], plA, false);
                plB = __builtin_amdgcn_fdot2(h23, w2h[mt][1], plB, false);
            }
            float logit = plA + plB;
            logit += __shfl_xor(logit, 16);
            logit += __shfl_xor(logit, 32);
            if (lane < 16) s_l[smp][31 * lane + 16 * sub + t] = logit + bias2;

            // advance (r,c) -> next pair (branchless)
            ++pc;
            const int wrap = (pc >= 32) ? 1 : 0;
            pr += wrap;
            pc = wrap ? (pr + 1) : pc;
        }
    }
    __syncthreads();   // bar2: all 496 logits of both samples in LDS

    // ---- softmax: full 496, duplicated per wave (deterministic) ----
    float lv[8], mx = -1e30f;
    #pragma unroll
    for (int k = 0; k < 8; ++k) {
        const int p = (k << 6) + lane;
        lv[k] = (p < NP) ? s_l[smp][p] : -1e30f;
        mx = fmaxf(mx, lv[k]);
    }
    #pragma unroll
    for (int off = 1; off < 64; off <<= 1) mx = fmaxf(mx, __shfl_xor(mx, off));

    float ev[8], se = 0.0f;
    #pragma unroll
    for (int k = 0; k < 8; ++k) {
        const int p = (k << 6) + lane;
        ev[k] = (p < NP) ? __expf(lv[k] - mx) : 0.0f;
        se += ev[k];
    }
    #pragma unroll
    for (int off = 1; off < 64; off <<= 1) se += __shfl_xor(se, off);
    const float inv = 1.0f / se;

    // ---- scatter this wave's half of the weights; write attn ----
    float* __restrict__ attn_b = attn + (size_t)b * NP;
    #pragma unroll
    for (int k = 0; k < 4; ++k) {
        const int kk = (sub << 2) + k;
        const int p = (kk << 6) + lane;
        if (p < NP) {
            const float w = ev[kk] * inv;
            attn_b[p] = w;
            const unsigned short rc = s_rc[p];
            const int r = rc & 255, c = rc >> 8;
            const _Float16 wh = (_Float16)w;
            Wt[smp][r][c] = wh;
            Wt[smp][c][r] = wh;
        }
    }
    __syncthreads();   // bar3: Wt complete

    // ---- phase 3 as GEMM: Y = Wt @ X; out = 0.5 * sum_r x*y. nt split by sub ----
    f16x8 wa[2], xbf[2];
    #pragma unroll
    for (int mt = 0; mt < 2; ++mt)
        wa[mt] = *(const f16x8*)&Wt[smp][mt * 16 + nlane][g * 8];
    #pragma unroll
    for (int j = 0; j < 2; ++j) {
        const int nt = 2 * sub + j;
        xbf[j] = *(const f16x8*)&xT[smp][nt * 16 + nlane][g * 8];
    }

    f32x4 y[2][2];
    #pragma unroll
    for (int mt = 0; mt < 2; ++mt)
        #pragma unroll
        for (int j = 0; j < 2; ++j) {
            y[mt][j] = (f32x4)0.0f;
            y[mt][j] = __builtin_amdgcn_mfma_f32_16x16x32_f16(wa[mt], xbf[j], y[mt][j], 0, 0, 0);
        }

    float po[2] = {0.f, 0.f};
    #pragma unroll
    for (int j = 0; j < 2; ++j) {
        const int nt = 2 * sub + j;
        #pragma unroll
        for (int mt = 0; mt < 2; ++mt) {
            const f16x4 xv = *(const f16x4*)&xT[smp][nt * 16 + nlane][mt * 16 + g * 4];
            po[j] += (float)xv[0] * y[mt][j][0];
            po[j] += (float)xv[1] * y[mt][j][1];
            po[j] += (float)xv[2] * y[mt][j][2];
            po[j] += (float)xv[3] * y[mt][j][3];
        }
        po[j] += __shfl_xor(po[j], 16);
        po[j] += __shfl_xor(po[j], 32);
    }
    if (lane < 16) {
        float* __restrict__ ob = out + (size_t)b * NE;
        #pragma unroll
        for (int j = 0; j < 2; ++j)
            ob[(2 * sub + j) * 16 + lane] = 0.5f * po[j];
    }
}

extern "C" void kernel_launch(void* const* d_in, const int* in_sizes, int n_in,
                              void* d_out, int out_size, void* d_ws, size_t ws_size,
                              hipStream_t stream) {
    const float* x  = (const float*)d_in[0];
    const float* W1 = (const float*)d_in[1];
    const float* b1 = (const float*)d_in[2];
    const float* w2 = (const float*)d_in[3];
    const float* b2 = (const float*)d_in[4];

    const int B = in_sizes[0] / (NF * NE);             // 2048
    float* out_p  = (float*)d_out;                     // (B,1,64) flat
    float* attn_p = (float*)d_out + (size_t)B * NE;    // (B,496,1) flat

    afm_fwd<<<(B + 1) / 2, 256, 0, stream>>>(x, W1, b1, w2, b2, out_p, attn_p, B);
}

// Round 15
// 21.276 us; speedup vs baseline: 1.3173x; 1.1512x over previous
//
#include <hip/hip_runtime.h>
#include <math.h>

#define NF 32
#define NE 64
#define NA 64
#define NP 496

typedef __attribute__((ext_vector_type(8))) _Float16 f16x8;
typedef __attribute__((ext_vector_type(4))) _Float16 f16x4;
typedef __attribute__((ext_vector_type(2))) __fp16   h16x2;
typedef __attribute__((ext_vector_type(4))) float    f32x4;

#define W1T_S 72
#define XT_S  40
#define WT_S  40

// R8 structure + R13 VALU cuts, occupancy fixed: launch_bounds(256,4) pins
// <=128 VGPR / 4 blocks/CU (R13's (256,1) let VGPR balloon -> 2 blocks/CU).
// Phase 1 software-pipelined: next tile's 4 ds_read_b128 issued before the
// current tile's MFMA+epilogue (breaks the ~120cy DS latency off the chain).
__global__ __launch_bounds__(256, 4) void afm_fwd(
    const float* __restrict__ x,    // (B,32,64)
    const float* __restrict__ W1,   // (64,64)
    const float* __restrict__ b1,   // (64)
    const float* __restrict__ w2,   // (64,1)
    const float* __restrict__ b2,   // (1)
    float* __restrict__ out,        // (B,64)
    float* __restrict__ attn,       // (B,496)
    int B)
{
    const int tid   = threadIdx.x;
    const int lane  = tid & 63;
    const int wv    = tid >> 6;
    const int smp   = wv >> 1;
    const int sub   = wv & 1;
    const int nlane = lane & 15;
    const int g     = lane >> 4;

    __shared__ __align__(16) _Float16 W1t[64][W1T_S];      // 9216 B
    __shared__ __align__(16) _Float16 xh[2][8][NF][8];     // 8192 B
    __shared__ __align__(16) _Float16 xT[2][NE][XT_S];     // 10240 B
    __shared__ __align__(16) _Float16 Wt[2][NF][WT_S];     // 5120 B
    __shared__ float s_l[2][NP];                           // 3968 B
    __shared__ unsigned short s_rc[512];                   // 1024 B

    // ---- block-cooperative: W1 -> W1t (f16, transposed), pair table ----
    {
        const int e = tid & 63, a0 = (tid >> 6) << 4;
        const float* wr = W1 + e * NA + a0;
        #pragma unroll
        for (int i = 0; i < 4; ++i) {
            const float4 v = *(const float4*)(wr + 4 * i);
            W1t[a0 + 4*i + 0][e] = (_Float16)v.x;
            W1t[a0 + 4*i + 1][e] = (_Float16)v.y;
            W1t[a0 + 4*i + 2][e] = (_Float16)v.z;
            W1t[a0 + 4*i + 3][e] = (_Float16)v.w;
        }
    }
    for (int p = tid; p < 512; p += 256) {
        const int pp = (p < NP) ? p : NP - 1;
        const float sq = sqrtf((float)(3969 - 8 * pp));
        int r = (int)((63.0f - sq) * 0.5f);
        int st = (r * (63 - r)) >> 1;
        if (pp < st) { --r; st = (r * (63 - r)) >> 1; }
        else { const int st2 = ((r + 1) * (62 - r)) >> 1; if (pp >= st2) { ++r; st = st2; } }
        const int c = pp - st + r + 1;
        s_rc[p] = (unsigned short)(r | (c << 8));
    }

    int b = blockIdx.x * 2 + smp;
    if (b >= B) b = B - 1;

    // ---- zero Wt[smp] (ordering rides bar1+bar2) ----
    {
        unsigned int* wz = (unsigned int*)&Wt[smp][0][0];
        #pragma unroll
        for (int i = 0; i < 5; ++i) {
            const int idx = i * 64 + lane;
            if (idx < 320) wz[sub * 320 + idx] = 0u;
        }
    }

    // ---- stage x[b] halves -> xh (e-subtiled) and xT (transposed) ----
    const float* __restrict__ xb = x + (size_t)b * (NF * NE);
    {
        const int r  = sub * 16 + (lane >> 2);
        const int e0 = (lane & 3) << 4;
        #pragma unroll
        for (int i = 0; i < 4; ++i) {
            const int e = e0 + 4 * i;
            const float4 v = *(const float4*)(xb + r * NE + e);
            f16x4 hv = { (_Float16)v.x, (_Float16)v.y, (_Float16)v.z, (_Float16)v.w };
            *(f16x4*)&xh[smp][e >> 3][r][e & 7] = hv;
            xT[smp][e + 0][r] = hv[0];
            xT[smp][e + 1][r] = hv[1];
            xT[smp][e + 2][r] = hv[2];
            xT[smp][e + 3][r] = hv[3];
        }
    }

    // ---- per-lane (r,c) for striped pairs p = 31*nlane + 16*sub + t ----
    int pr, pc;
    {
        const int p0 = 31 * nlane + 16 * sub;
        const float sq = sqrtf((float)(3969 - 8 * p0));
        int r = (int)((63.0f - sq) * 0.5f);
        int st = (r * (63 - r)) >> 1;
        if (p0 < st) { --r; st = (r * (63 - r)) >> 1; }
        else { const int st2 = ((r + 1) * (62 - r)) >> 1; if (p0 >= st2) { ++r; st = st2; } }
        pr = r;
        pc = p0 - st + r + 1;
    }
    __syncthreads();   // bar1

    // ---- W1 A-frags from LDS (8 x ds_read_b128) ----
    f16x8 w1f[2][4];
    #pragma unroll
    for (int s = 0; s < 2; ++s)
        #pragma unroll
        for (int mt = 0; mt < 4; ++mt)
            w1f[s][mt] = *(const f16x8*)&W1t[mt * 16 + nlane][s * 32 + g * 8];

    f32x4 b1q[4];
    h16x2 w2h[4][2];
    #pragma unroll
    for (int mt = 0; mt < 4; ++mt) {
        b1q[mt] = *(const f32x4*)(b1 + mt * 16 + g * 4);
        const f32x4 wq = *(const f32x4*)(w2 + mt * 16 + g * 4);
        w2h[mt][0] = (h16x2){ (__fp16)wq[0], (__fp16)wq[1] };
        w2h[mt][1] = (h16x2){ (__fp16)wq[2], (__fp16)wq[3] };
    }
    const float bias2 = b2[0];
    const h16x2 zz = { (__fp16)0.0f, (__fp16)0.0f };

    // ---- phase 1, software-pipelined: prefetch tile t+1 before computing t ----
    f16x8 xr0c = *(const f16x8*)&xh[smp][g][pr][0];
    f16x8 xc0c = *(const f16x8*)&xh[smp][g][pc][0];
    f16x8 xr1c = *(const f16x8*)&xh[smp][4 + g][pr][0];
    f16x8 xc1c = *(const f16x8*)&xh[smp][4 + g][pc][0];

    #pragma unroll
    for (int t = 0; t < 16; ++t) {
        if (16 * sub + t < 31) {
            // advance rc to next pair; guarded prefetch into *n
            int npc = pc + 1;
            const int wrap = (npc >= 32) ? 1 : 0;
            const int npr = pr + wrap;
            npc = wrap ? (npr + 1) : npc;
            f16x8 xr0n, xc0n, xr1n, xc1n;
            if (16 * sub + t + 1 < 31) {           // uniform guard; masks the one OOB advance
                xr0n = *(const f16x8*)&xh[smp][g][npr][0];
                xc0n = *(const f16x8*)&xh[smp][g][npc][0];
                xr1n = *(const f16x8*)&xh[smp][4 + g][npr][0];
                xc1n = *(const f16x8*)&xh[smp][4 + g][npc][0];
            }

            const f16x8 af0 = xr0c * xc0c;
            const f16x8 af1 = xr1c * xc1c;

            f32x4 acc[4];
            __builtin_amdgcn_s_setprio(1);
            #pragma unroll
            for (int mt = 0; mt < 4; ++mt)         // b1 folded into C-operand
                acc[mt] = __builtin_amdgcn_mfma_f32_16x16x32_f16(w1f[0][mt], af0, b1q[mt], 0, 0, 0);
            #pragma unroll
            for (int mt = 0; mt < 4; ++mt)
                acc[mt] = __builtin_amdgcn_mfma_f32_16x16x32_f16(w1f[1][mt], af1, acc[mt], 0, 0, 0);
            __builtin_amdgcn_s_setprio(0);

            // packed relu-dot: cvt_pkrtz -> pk_max -> fdot2 (f32 accumulate)
            float plA = 0.f, plB = 0.f;
            #pragma unroll
            for (int mt = 0; mt < 4; ++mt) {
                h16x2 h01 = __builtin_amdgcn_cvt_pkrtz(acc[mt][0], acc[mt][1]);
                h16x2 h23 = __builtin_amdgcn_cvt_pkrtz(acc[mt][2], acc[mt][3]);
                h01 = __builtin_elementwise_max(h01, zz);
                h23 = __builtin_elementwise_max(h23, zz);
                plA = __builtin_amdgcn_fdot2(h01, w2h[mt][0], plA, false);
                plB = __builtin_amdgcn_fdot2(h23, w2h[mt][1], plB, false);
            }
            float logit = plA + plB;
            logit += __shfl_xor(logit, 16);
            logit += __shfl_xor(logit, 32);
            if (lane < 16) s_l[smp][31 * lane + 16 * sub + t] = logit + bias2;

            pr = npr; pc = npc;
            xr0c = xr0n; xc0c = xc0n; xr1c = xr1n; xc1c = xc1n;
        }
    }
    __syncthreads();   // bar2: all 496 logits of both samples in LDS

    // ---- softmax: full 496, duplicated per wave (deterministic) ----
    float lv[8], mx = -1e30f;
    #pragma unroll
    for (int k = 0; k < 8; ++k) {
        const int p = (k << 6) + lane;
        lv[k] = (p < NP) ? s_l[smp][p] : -1e30f;
        mx = fmaxf(mx, lv[k]);
    }
    #pragma unroll
    for (int off = 1; off < 64; off <<= 1) mx = fmaxf(mx, __shfl_xor(mx, off));

    float ev[8], se = 0.0f;
    #pragma unroll
    for (int k = 0; k < 8; ++k) {
        const int p = (k << 6) + lane;
        ev[k] = (p < NP) ? __expf(lv[k] - mx) : 0.0f;
        se += ev[k];
    }
    #pragma unroll
    for (int off = 1; off < 64; off <<= 1) se += __shfl_xor(se, off);
    const float inv = 1.0f / se;

    // ---- scatter this wave's half of the weights; write attn ----
    float* __restrict__ attn_b = attn + (size_t)b * NP;
    #pragma unroll
    for (int k = 0; k < 4; ++k) {
        const int kk = (sub << 2) + k;
        const int p = (kk << 6) + lane;
        if (p < NP) {
            const float w = ev[kk] * inv;
            attn_b[p] = w;
            const unsigned short rc = s_rc[p];
            const int r = rc & 255, c = rc >> 8;
            const _Float16 wh = (_Float16)w;
            Wt[smp][r][c] = wh;
            Wt[smp][c][r] = wh;
        }
    }
    __syncthreads();   // bar3: Wt complete

    // ---- phase 3 as GEMM: Y = Wt @ X; out = 0.5 * sum_r x*y ----
    f16x8 wa[2], xbf[2];
    #pragma unroll
    for (int mt = 0; mt < 2; ++mt)
        wa[mt] = *(const f16x8*)&Wt[smp][mt * 16 + nlane][g * 8];
    #pragma unroll
    for (int j = 0; j < 2; ++j) {
        const int nt = 2 * sub + j;
        xbf[j] = *(const f16x8*)&xT[smp][nt * 16 + nlane][g * 8];
    }

    f32x4 y[2][2];
    #pragma unroll
    for (int mt = 0; mt < 2; ++mt)
        #pragma unroll
        for (int j = 0; j < 2; ++j) {
            y[mt][j] = (f32x4)0.0f;
            y[mt][j] = __builtin_amdgcn_mfma_f32_16x16x32_f16(wa[mt], xbf[j], y[mt][j], 0, 0, 0);
        }

    float po[2] = {0.f, 0.f};
    #pragma unroll
    for (int j = 0; j < 2; ++j) {
        const int nt = 2 * sub + j;
        #pragma unroll
        for (int mt = 0; mt < 2; ++mt) {
            const f16x4 xv = *(const f16x4*)&xT[smp][nt * 16 + nlane][mt * 16 + g * 4];
            po[j] += (float)xv[0] * y[mt][j][0];
            po[j] += (float)xv[1] * y[mt][j][1];
            po[j] += (float)xv[2] * y[mt][j][2];
            po[j] += (float)xv[3] * y[mt][j][3];
        }
        po[j] += __shfl_xor(po[j], 16);
        po[j] += __shfl_xor(po[j], 32);
    }
    if (lane < 16) {
        float* __restrict__ ob = out + (size_t)b * NE;
        #pragma unroll
        for (int j = 0; j < 2; ++j)
            ob[(2 * sub + j) * 16 + lane] = 0.5f * po[j];
    }
}

extern "C" void kernel_launch(void* const* d_in, const int* in_sizes, int n_in,
                              void* d_out, int out_size, void* d_ws, size_t ws_size,
                              hipStream_t stream) {
    const float* x  = (const float*)d_in[0];
    const float* W1 = (const float*)d_in[1];
    const float* b1 = (const float*)d_in[2];
    const float* w2 = (const float*)d_in[3];
    const float* b2 = (const float*)d_in[4];

    const int B = in_sizes[0] / (NF * NE);             // 2048
    float* out_p  = (float*)d_out;                     // (B,1,64) flat
    float* attn_p = (float*)d_out + (size_t)B * NE;    // (B,496,1) flat

    afm_fwd<<<(B + 1) / 2, 256, 0, stream>>>(x, W1, b1, w2, b2, out_p, attn_p, B);
}